// Round 7
// baseline (391.582 us; speedup 1.0000x reference)
//
#include <hip/hip_runtime.h>
#include <hip/hip_bf16.h>
#include <stdint.h>
#include <math.h>

#define SEQ 4096
#define DIM 1024
#define NHEADS 16
#define DHEAD 64
#define INNER 1024

typedef __hip_bfloat16 bf16;
typedef __attribute__((ext_vector_type(8))) short short8;
typedef __attribute__((ext_vector_type(4))) float floatx4;

// async global->LDS, 16B per lane; lane i's 16B lands at dest + i*16.
__device__ __forceinline__ void gll16(const bf16* g, bf16* l) {
    __builtin_amdgcn_global_load_lds(
        (const __attribute__((address_space(1))) unsigned int*)g,
        (__attribute__((address_space(3))) unsigned int*)l,
        16, 0, 0);
}

__device__ __forceinline__ unsigned short f2bf_bits(float f) {
    bf16 h = __float2bfloat16(f);
    return *reinterpret_cast<unsigned short*>(&h);
}

__device__ __forceinline__ uint2 pack4bf(float a, float b, float c, float d) {
    __hip_bfloat162 lo = __float22bfloat162_rn(float2{a, b});
    __hip_bfloat162 hi = __float22bfloat162_rn(float2{c, d});
    uint2 r;
    r.x = *reinterpret_cast<unsigned*>(&lo);
    r.y = *reinterpret_cast<unsigned*>(&hi);
    return r;
}

// ---------------- convert x (fp32 -> bf16), 4 elems/thread ----------------
__global__ __launch_bounds__(256) void convert_x_kernel(const float* __restrict__ x,
                                                        bf16* __restrict__ xb) {
    int i = (blockIdx.x * 256 + threadIdx.x) * 4;
    float4 f = *reinterpret_cast<const float4*>(x + i);
    unsigned long long p = (unsigned long long)f2bf_bits(f.x)
                         | ((unsigned long long)f2bf_bits(f.y) << 16)
                         | ((unsigned long long)f2bf_bits(f.z) << 32)
                         | ((unsigned long long)f2bf_bits(f.w) << 48);
    *reinterpret_cast<unsigned long long*>(xb + i) = p;
}

// ------------- transpose + convert weights: W[k][n] -> Wt[n][k] bf16 -------------
__global__ __launch_bounds__(256) void transpose_w_kernel(
        const float* __restrict__ W0, const float* __restrict__ W1,
        const float* __restrict__ W2, const float* __restrict__ W3,
        bf16* __restrict__ T0, bf16* __restrict__ T1,
        bf16* __restrict__ T2, bf16* __restrict__ T3) {
    const float* W; bf16* T;
    switch (blockIdx.z) {
        case 0:  W = W0; T = T0; break;
        case 1:  W = W1; T = T1; break;
        case 2:  W = W2; T = T2; break;
        default: W = W3; T = T3; break;
    }
    __shared__ float tile[32][33];
    int k0 = blockIdx.x * 32, n0 = blockIdx.y * 32;
    int tx = threadIdx.x, ty = threadIdx.y;
    #pragma unroll
    for (int i = 0; i < 4; i++)
        tile[ty + 8 * i][tx] = W[(size_t)(k0 + ty + 8 * i) * 1024 + n0 + tx];
    __syncthreads();
    #pragma unroll
    for (int i = 0; i < 4; i++)
        T[(size_t)(n0 + ty + 8 * i) * 1024 + k0 + tx] = __float2bfloat16(tile[tx][ty + 8 * i]);
}

// ---------------- 128x128 bf16 MFMA GEMM tile body (K=1024), m97-style ----------------
__device__ __forceinline__ void gemm128_body(const bf16* __restrict__ A,
                                             const bf16* __restrict__ Bt,
                                             int m0, int n0, floatx4 acc[4][4]) {
    __shared__ __align__(16) bf16 As[8192];
    __shared__ __align__(16) bf16 Bs[8192];
    const int tid = threadIdx.x;
    const int wave = tid >> 6;
    const int lane = tid & 63;
    const int l15 = lane & 15;
    const int quad = lane >> 4;

    #pragma unroll
    for (int i = 0; i < 4; i++)
        #pragma unroll
        for (int j = 0; j < 4; j++)
            acc[i][j] = (floatx4){0.f, 0.f, 0.f, 0.f};

    for (int k0 = 0; k0 < 1024; k0 += 64) {
        __syncthreads();
        #pragma unroll
        for (int j = 0; j < 4; j++) {
            int t = wave * 4 + j;
            int row = (t >> 1) * 16 + l15;
            int kb = (t & 1) * 32 + quad * 8;
            gll16(A + (size_t)(m0 + row) * 1024 + k0 + kb, &As[t * 512]);
            gll16(Bt + (size_t)(n0 + row) * 1024 + k0 + kb, &Bs[t * 512]);
        }
        __syncthreads();
        #pragma unroll
        for (int ks = 0; ks < 2; ks++) {
            short8 af[4], bfr[4];
            #pragma unroll
            for (int i = 0; i < 4; i++)
                af[i] = *reinterpret_cast<const short8*>(
                    &As[((((wave >> 1) * 4 + i) * 2 + ks) * 512) + lane * 8]);
            #pragma unroll
            for (int j = 0; j < 4; j++)
                bfr[j] = *reinterpret_cast<const short8*>(
                    &Bs[((((wave & 1) * 4 + j) * 2 + ks) * 512) + lane * 8]);
            #pragma unroll
            for (int i = 0; i < 4; i++)
                #pragma unroll
                for (int j = 0; j < 4; j++)
                    acc[i][j] = __builtin_amdgcn_mfma_f32_16x16x32_bf16(af[i], bfr[j], acc[i][j], 0, 0, 0);
        }
    }
}

// ---------------- QKV projection ----------------
// z=0: Q (scaled by beta*log2e, head-major [h][seq][64])
// z=1: K (head-major [h][seq][64])
// z=2: V written TRANSPOSED directly: Vt[h][d][seq] (b64 packed stores — the 4
//      acc elements per (i,j) are 4 consecutive seq rows => contiguous in Vt).
__global__ __launch_bounds__(256) void qkv_gemm_kernel(
        const bf16* __restrict__ xb,
        const bf16* __restrict__ Wqt, const bf16* __restrict__ Wkt, const bf16* __restrict__ Wvt,
        bf16* __restrict__ Qh, bf16* __restrict__ Kh, bf16* __restrict__ Vt) {
    const bf16* Bt;
    if (blockIdx.z == 0)      Bt = Wqt;
    else if (blockIdx.z == 1) Bt = Wkt;
    else                      Bt = Wvt;
    int n0 = blockIdx.x * 128, m0 = blockIdx.y * 128;
    floatx4 acc[4][4];
    gemm128_body(xb, Bt, m0, n0, acc);

    const int tid = threadIdx.x, wave = tid >> 6, lane = tid & 63;
    const int l15 = lane & 15, quad = lane >> 4;
    const int wm = (wave >> 1) * 64, wn = (wave & 1) * 64;
    if (blockIdx.z == 2) {
        #pragma unroll
        for (int i = 0; i < 4; i++)
            #pragma unroll
            for (int j = 0; j < 4; j++) {
                int col = n0 + wn + j * 16 + l15;
                int h = col >> 6, d = col & 63;
                int row0 = m0 + wm + i * 16 + quad * 4;
                uint2 v = pack4bf(acc[i][j][0], acc[i][j][1], acc[i][j][2], acc[i][j][3]);
                *reinterpret_cast<uint2*>(Vt + ((size_t)h * DHEAD + d) * SEQ + row0) = v;
            }
    } else {
        bf16* O = (blockIdx.z == 0) ? Qh : Kh;
        float scale = (blockIdx.z == 0) ? 0.125f * 1.4426950408889634f : 1.0f;
        #pragma unroll
        for (int i = 0; i < 4; i++)
            #pragma unroll
            for (int j = 0; j < 4; j++) {
                int col = n0 + wn + j * 16 + l15;
                int h = col >> 6, d = col & 63;
                #pragma unroll
                for (int r = 0; r < 4; r++) {
                    int row = m0 + wm + i * 16 + quad * 4 + r;
                    O[((size_t)h * SEQ + row) * DHEAD + d] = __float2bfloat16(acc[i][j][r] * scale);
                }
            }
    }
}

// ---------------- output projection: out = Oa @ Wo + bo (fp32 out) ----------------
__global__ __launch_bounds__(256) void out_gemm_kernel(
        const bf16* __restrict__ Oa, const bf16* __restrict__ Wot,
        const float* __restrict__ bo, float* __restrict__ out) {
    int n0 = blockIdx.x * 128, m0 = blockIdx.y * 128;
    floatx4 acc[4][4];
    gemm128_body(Oa, Wot, m0, n0, acc);

    const int tid = threadIdx.x, wave = tid >> 6, lane = tid & 63;
    const int l15 = lane & 15, quad = lane >> 4;
    const int wm = (wave >> 1) * 64, wn = (wave & 1) * 64;
    #pragma unroll
    for (int i = 0; i < 4; i++)
        #pragma unroll
        for (int j = 0; j < 4; j++) {
            int col = n0 + wn + j * 16 + l15;
            float b = bo[col];
            #pragma unroll
            for (int r = 0; r < 4; r++) {
                int row = m0 + wm + i * 16 + quad * 4 + r;
                out[(size_t)row * DIM + col] = acc[i][j][r] + b;
            }
        }
}

// ---------------- causal flash attention (R4 skeleton + V-in-registers) ----------------
// Block = 4 waves x 16 q-rows; BK=128. Sᵀ = K·Qᵀ (per-lane softmax denom; Q
// pre-scaled by beta*log2e => p = exp2(s)). K tile staged via global_load_lds
// (fragment-packed, linear b128 reads). V read direct from global into registers
// in two 8-fragment batches issued far ahead of their PV use (latency covered by
// softmax). LDS = K 16K + Ps 16K = 32K; launch_bounds(256,4) caps VGPR at 128
// => 4 blocks/CU. head = id&15 pins 2 heads/XCD (L2-resident, proven R4).
// Zigzag qt: any co-resident set {id+256k} has constant total causal work.
__global__ __launch_bounds__(256, 4) void attention_kernel(
        const bf16* __restrict__ Qh, const bf16* __restrict__ Kh,
        const bf16* __restrict__ Vt, bf16* __restrict__ Oa) {
    __shared__ __align__(16) bf16 Ksh[8192];     // 16 KB: frag t = keygrp*2 + khalf
    __shared__ __align__(16) bf16 Ps[4][2048];   // 4 KB/wave: frag s = key/32
    const int tid = threadIdx.x, wave = tid >> 6, lane = tid & 63;
    const int l15 = lane & 15, quad = lane >> 4;
    const int id = blockIdx.x;
    const int head = id & 15;                    // XCD id&7 serves heads {h, h+8}
    const int rid = id >> 4;                     // 0..63
    const int low = rid & 15, hi = rid >> 4;     // hi 0..3
    const int qt = hi * 16 + ((hi & 1) ? (15 - low) : low);  // zigzag-balanced
    const int qw = qt * 64 + wave * 16;          // wave's q-row base
    const size_t hoff = (size_t)head * SEQ * DHEAD;
    const bf16* Qb = Qh + hoff;
    const bf16* Kb = Kh + hoff;
    const bf16* Vb = Vt + hoff;                  // [d][seq]

    // Q as B-operand fragments: lane n = l15 -> q-row qw+l15, k along d
    short8 bq[2];
    #pragma unroll
    for (int s = 0; s < 2; s++)
        bq[s] = *reinterpret_cast<const short8*>(
            Qb + (size_t)(qw + l15) * DHEAD + s * 32 + quad * 8);

    floatx4 acc_o[4];                            // Oᵀ: d = c*16+quad*4+r, q = l15
    #pragma unroll
    for (int c = 0; c < 4; c++) acc_o[c] = (floatx4){0.f, 0.f, 0.f, 0.f};
    float l_part = 0.f;                          // per-lane softmax denom partial

    const bf16* vp0 = Vb + (size_t)l15 * SEQ + quad * 8;  // + c*16*SEQ + kbase + s*32

    const int ntiles = (qt + 2) >> 1;            // BK=128: keys 0..qt*64+63
    for (int kt = 0; kt < ntiles; kt++) {
        const int kbase = kt * 128;
        __syncthreads();                         // prev-tile Ksh readers done
        #pragma unroll
        for (int j = 0; j < 4; j++) {
            int t = wave * 4 + j;                // 16 K frags across 4 waves
            gll16(Kb + (size_t)(kbase + (t >> 1) * 16 + l15) * DHEAD + (t & 1) * 32 + quad * 8,
                  &Ksh[t * 512]);
        }
        // V batch0 (s=0,1): issued now, consumed after softmax (latency hidden)
        short8 av0[2][4];
        #pragma unroll
        for (int s = 0; s < 2; s++)
            #pragma unroll
            for (int c = 0; c < 4; c++)
                av0[s][c] = *reinterpret_cast<const short8*>(
                    vp0 + (size_t)(c * 16) * SEQ + kbase + s * 32);
        __syncthreads();                         // K tile visible (drains vmcnt)

        // Sᵀ = K·Qᵀ: linear conflict-free b128 LDS reads
        floatx4 st[8];
        #pragma unroll
        for (int c = 0; c < 8; c++) st[c] = (floatx4){0.f, 0.f, 0.f, 0.f};
        #pragma unroll
        for (int c = 0; c < 8; c++) {
            short8 ak0 = *reinterpret_cast<const short8*>(&Ksh[(c * 2 + 0) * 512 + lane * 8]);
            short8 ak1 = *reinterpret_cast<const short8*>(&Ksh[(c * 2 + 1) * 512 + lane * 8]);
            st[c] = __builtin_amdgcn_mfma_f32_16x16x32_bf16(ak0, bq[0], st[c], 0, 0, 0);
            st[c] = __builtin_amdgcn_mfma_f32_16x16x32_bf16(ak1, bq[1], st[c], 0, 0, 0);
        }
        // V batch1 (s=2,3): issue before softmax, consumed at PV tail
        short8 av1[2][4];
        #pragma unroll
        for (int s = 0; s < 2; s++)
            #pragma unroll
            for (int c = 0; c < 4; c++)
                av1[s][c] = *reinterpret_cast<const short8*>(
                    vp0 + (size_t)(c * 16) * SEQ + kbase + (s + 2) * 32);
        // causal mask: key = kbase + c*16 + quad*4 + r, q = qw + l15
        if (kbase + 127 > qw) {                  // wave-uniform
            int base0 = kbase + quad * 4 - qw - l15;
            #pragma unroll
            for (int c = 0; c < 8; c++) {
                int base = base0 + c * 16;
                #pragma unroll
                for (int r = 0; r < 4; r++)
                    if (base + r > 0) st[c][r] = -1e30f;
            }
        }
        // p = exp2(s); per-lane denom; pack into fragment-layout Ps (b64 writes)
        #pragma unroll
        for (int c = 0; c < 8; c++) {
            float p0 = exp2f(st[c][0]);
            float p1 = exp2f(st[c][1]);
            float p2 = exp2f(st[c][2]);
            float p3 = exp2f(st[c][3]);
            l_part += (p0 + p1) + (p2 + p3);
            int elem = (c >> 1) * 512
                     + (l15 + 16 * ((c & 1) * 2 + (quad >> 1))) * 8 + (quad & 1) * 4;
            *reinterpret_cast<uint2*>(&Ps[wave][elem]) = pack4bf(p0, p1, p2, p3);
        }
        // Oᵀ += Vᵀ·Pᵀ (B-frag Pᵀ from per-wave LDS; in-wave RAW via lgkmcnt)
        #pragma unroll
        for (int s = 0; s < 2; s++) {
            short8 bp = *reinterpret_cast<const short8*>(&Ps[wave][s * 512 + lane * 8]);
            #pragma unroll
            for (int c = 0; c < 4; c++)
                acc_o[c] = __builtin_amdgcn_mfma_f32_16x16x32_bf16(av0[s][c], bp, acc_o[c], 0, 0, 0);
        }
        #pragma unroll
        for (int s = 0; s < 2; s++) {
            short8 bp = *reinterpret_cast<const short8*>(&Ps[wave][(s + 2) * 512 + lane * 8]);
            #pragma unroll
            for (int c = 0; c < 4; c++)
                acc_o[c] = __builtin_amdgcn_mfma_f32_16x16x32_bf16(av1[s][c], bp, acc_o[c], 0, 0, 0);
        }
    }
    // denom: sum the 4 quad-lanes holding this q-row
    float l = l_part;
    l += __shfl_xor(l, 16, 64);
    l += __shfl_xor(l, 32, 64);
    float rcp = 1.0f / l;
    // write O row-major [SEQ][INNER]: col q = qw+l15, rows d = c*16+quad*4+r
    const int q = qw + l15;
    #pragma unroll
    for (int c = 0; c < 4; c++) {
        uint2 v = pack4bf(acc_o[c][0] * rcp, acc_o[c][1] * rcp,
                          acc_o[c][2] * rcp, acc_o[c][3] * rcp);
        *reinterpret_cast<uint2*>(Oa + (size_t)q * INNER + head * DHEAD + c * 16 + quad * 4) = v;
    }
}

extern "C" void kernel_launch(void* const* d_in, const int* in_sizes, int n_in,
                              void* d_out, int out_size, void* d_ws, size_t ws_size,
                              hipStream_t stream) {
    const float* x  = (const float*)d_in[0];
    const float* Wq = (const float*)d_in[1];
    const float* Wk = (const float*)d_in[2];
    const float* Wv = (const float*)d_in[3];
    const float* Wo = (const float*)d_in[4];
    const float* bo = (const float*)d_in[5];
    float* out = (float*)d_out;

    char* ws = (char*)d_ws;
    size_t off = 0;
    bf16* xb  = (bf16*)(ws + off); off += (size_t)SEQ * DIM * 2;
    bf16* Wqt = (bf16*)(ws + off); off += (size_t)DIM * INNER * 2;
    bf16* Wkt = (bf16*)(ws + off); off += (size_t)DIM * INNER * 2;
    bf16* Wvt = (bf16*)(ws + off); off += (size_t)DIM * INNER * 2;
    bf16* Wot = (bf16*)(ws + off); off += (size_t)INNER * DIM * 2;
    bf16* Qh  = (bf16*)(ws + off); off += (size_t)NHEADS * SEQ * DHEAD * 2;
    bf16* Kh  = (bf16*)(ws + off); off += (size_t)NHEADS * SEQ * DHEAD * 2;
    bf16* Vtr = (bf16*)(ws + off); off += (size_t)NHEADS * DHEAD * SEQ * 2;
    bf16* Oa  = (bf16*)(ws + off); off += (size_t)SEQ * INNER * 2;  // ~48 MB total

    convert_x_kernel<<<(SEQ * DIM) / 1024, 256, 0, stream>>>(x, xb);
    transpose_w_kernel<<<dim3(32, 32, 4), dim3(32, 8), 0, stream>>>(Wq, Wk, Wv, Wo,
                                                                    Wqt, Wkt, Wvt, Wot);
    qkv_gemm_kernel<<<dim3(8, 32, 3), 256, 0, stream>>>(xb, Wqt, Wkt, Wvt, Qh, Kh, Vtr);
    attention_kernel<<<1024, 256, 0, stream>>>(Qh, Kh, Vtr, Oa);
    out_gemm_kernel<<<dim3(8, 32), 256, 0, stream>>>(Oa, Wot, bo, out);
}

// Round 8
// 267.150 us; speedup vs baseline: 1.4658x; 1.4658x over previous
//
#include <hip/hip_runtime.h>
#include <hip/hip_bf16.h>
#include <stdint.h>
#include <math.h>

#define SEQ 4096
#define DIM 1024
#define NHEADS 16
#define DHEAD 64
#define INNER 1024

typedef __hip_bfloat16 bf16;
typedef __attribute__((ext_vector_type(8))) short short8;
typedef __attribute__((ext_vector_type(4))) float floatx4;

// async global->LDS, 16B per lane; lane i's 16B lands at dest + i*16.
__device__ __forceinline__ void gll16(const bf16* g, bf16* l) {
    __builtin_amdgcn_global_load_lds(
        (const __attribute__((address_space(1))) unsigned int*)g,
        (__attribute__((address_space(3))) unsigned int*)l,
        16, 0, 0);
}

__device__ __forceinline__ unsigned short f2bf_bits(float f) {
    bf16 h = __float2bfloat16(f);
    return *reinterpret_cast<unsigned short*>(&h);
}

__device__ __forceinline__ uint2 pack4bf(float a, float b, float c, float d) {
    __hip_bfloat162 lo = __float22bfloat162_rn(float2{a, b});
    __hip_bfloat162 hi = __float22bfloat162_rn(float2{c, d});
    uint2 r;
    r.x = *reinterpret_cast<unsigned*>(&lo);
    r.y = *reinterpret_cast<unsigned*>(&hi);
    return r;
}

// ---------------- convert x (fp32 -> bf16), 4 elems/thread ----------------
__global__ __launch_bounds__(256) void convert_x_kernel(const float* __restrict__ x,
                                                        bf16* __restrict__ xb) {
    int i = (blockIdx.x * 256 + threadIdx.x) * 4;
    float4 f = *reinterpret_cast<const float4*>(x + i);
    unsigned long long p = (unsigned long long)f2bf_bits(f.x)
                         | ((unsigned long long)f2bf_bits(f.y) << 16)
                         | ((unsigned long long)f2bf_bits(f.z) << 32)
                         | ((unsigned long long)f2bf_bits(f.w) << 48);
    *reinterpret_cast<unsigned long long*>(xb + i) = p;
}

// ------------- transpose + convert weights: W[k][n] -> Wt[n][k] bf16 -------------
__global__ __launch_bounds__(256) void transpose_w_kernel(
        const float* __restrict__ W0, const float* __restrict__ W1,
        const float* __restrict__ W2, const float* __restrict__ W3,
        bf16* __restrict__ T0, bf16* __restrict__ T1,
        bf16* __restrict__ T2, bf16* __restrict__ T3) {
    const float* W; bf16* T;
    switch (blockIdx.z) {
        case 0:  W = W0; T = T0; break;
        case 1:  W = W1; T = T1; break;
        case 2:  W = W2; T = T2; break;
        default: W = W3; T = T3; break;
    }
    __shared__ float tile[32][33];
    int k0 = blockIdx.x * 32, n0 = blockIdx.y * 32;
    int tx = threadIdx.x, ty = threadIdx.y;
    #pragma unroll
    for (int i = 0; i < 4; i++)
        tile[ty + 8 * i][tx] = W[(size_t)(k0 + ty + 8 * i) * 1024 + n0 + tx];
    __syncthreads();
    #pragma unroll
    for (int i = 0; i < 4; i++)
        T[(size_t)(n0 + ty + 8 * i) * 1024 + k0 + tx] = __float2bfloat16(tile[tx][ty + 8 * i]);
}

// ---------------- 128x128 bf16 MFMA GEMM tile body (K=1024), m97-style ----------------
__device__ __forceinline__ void gemm128_body(const bf16* __restrict__ A,
                                             const bf16* __restrict__ Bt,
                                             int m0, int n0, floatx4 acc[4][4]) {
    __shared__ __align__(16) bf16 As[8192];
    __shared__ __align__(16) bf16 Bs[8192];
    const int tid = threadIdx.x;
    const int wave = tid >> 6;
    const int lane = tid & 63;
    const int l15 = lane & 15;
    const int quad = lane >> 4;

    #pragma unroll
    for (int i = 0; i < 4; i++)
        #pragma unroll
        for (int j = 0; j < 4; j++)
            acc[i][j] = (floatx4){0.f, 0.f, 0.f, 0.f};

    for (int k0 = 0; k0 < 1024; k0 += 64) {
        __syncthreads();
        #pragma unroll
        for (int j = 0; j < 4; j++) {
            int t = wave * 4 + j;
            int row = (t >> 1) * 16 + l15;
            int kb = (t & 1) * 32 + quad * 8;
            gll16(A + (size_t)(m0 + row) * 1024 + k0 + kb, &As[t * 512]);
            gll16(Bt + (size_t)(n0 + row) * 1024 + k0 + kb, &Bs[t * 512]);
        }
        __syncthreads();
        #pragma unroll
        for (int ks = 0; ks < 2; ks++) {
            short8 af[4], bfr[4];
            #pragma unroll
            for (int i = 0; i < 4; i++)
                af[i] = *reinterpret_cast<const short8*>(
                    &As[((((wave >> 1) * 4 + i) * 2 + ks) * 512) + lane * 8]);
            #pragma unroll
            for (int j = 0; j < 4; j++)
                bfr[j] = *reinterpret_cast<const short8*>(
                    &Bs[((((wave & 1) * 4 + j) * 2 + ks) * 512) + lane * 8]);
            #pragma unroll
            for (int i = 0; i < 4; i++)
                #pragma unroll
                for (int j = 0; j < 4; j++)
                    acc[i][j] = __builtin_amdgcn_mfma_f32_16x16x32_bf16(af[i], bfr[j], acc[i][j], 0, 0, 0);
        }
    }
}

// ---------------- QKV projection ----------------
// z=0: Q (scaled by beta*log2e so attention uses exp2 directly; [h][seq][64])
// z=1: K ([h][seq][64])
// z=2: V written TRANSPOSED directly: Vt[h][d][seq] (b64 packed stores — the 4
//      acc elements per (i,j) are 4 consecutive seq rows => contiguous in Vt).
__global__ __launch_bounds__(256) void qkv_gemm_kernel(
        const bf16* __restrict__ xb,
        const bf16* __restrict__ Wqt, const bf16* __restrict__ Wkt, const bf16* __restrict__ Wvt,
        bf16* __restrict__ Qh, bf16* __restrict__ Kh, bf16* __restrict__ Vt) {
    const bf16* Bt;
    if (blockIdx.z == 0)      Bt = Wqt;
    else if (blockIdx.z == 1) Bt = Wkt;
    else                      Bt = Wvt;
    int n0 = blockIdx.x * 128, m0 = blockIdx.y * 128;
    floatx4 acc[4][4];
    gemm128_body(xb, Bt, m0, n0, acc);

    const int tid = threadIdx.x, wave = tid >> 6, lane = tid & 63;
    const int l15 = lane & 15, quad = lane >> 4;
    const int wm = (wave >> 1) * 64, wn = (wave & 1) * 64;
    if (blockIdx.z == 2) {
        #pragma unroll
        for (int i = 0; i < 4; i++)
            #pragma unroll
            for (int j = 0; j < 4; j++) {
                int col = n0 + wn + j * 16 + l15;
                int h = col >> 6, d = col & 63;
                int row0 = m0 + wm + i * 16 + quad * 4;
                uint2 v = pack4bf(acc[i][j][0], acc[i][j][1], acc[i][j][2], acc[i][j][3]);
                *reinterpret_cast<uint2*>(Vt + ((size_t)h * DHEAD + d) * SEQ + row0) = v;
            }
    } else {
        bf16* O = (blockIdx.z == 0) ? Qh : Kh;
        float scale = (blockIdx.z == 0) ? 0.125f * 1.4426950408889634f : 1.0f;
        #pragma unroll
        for (int i = 0; i < 4; i++)
            #pragma unroll
            for (int j = 0; j < 4; j++) {
                int col = n0 + wn + j * 16 + l15;
                int h = col >> 6, d = col & 63;
                #pragma unroll
                for (int r = 0; r < 4; r++) {
                    int row = m0 + wm + i * 16 + quad * 4 + r;
                    O[((size_t)h * SEQ + row) * DHEAD + d] = __float2bfloat16(acc[i][j][r] * scale);
                }
            }
    }
}

// ---------------- output projection: out = Oa @ Wo + bo (fp32 out) ----------------
__global__ __launch_bounds__(256) void out_gemm_kernel(
        const bf16* __restrict__ Oa, const bf16* __restrict__ Wot,
        const float* __restrict__ bo, float* __restrict__ out) {
    int n0 = blockIdx.x * 128, m0 = blockIdx.y * 128;
    floatx4 acc[4][4];
    gemm128_body(Oa, Wot, m0, n0, acc);

    const int tid = threadIdx.x, wave = tid >> 6, lane = tid & 63;
    const int l15 = lane & 15, quad = lane >> 4;
    const int wm = (wave >> 1) * 64, wn = (wave & 1) * 64;
    #pragma unroll
    for (int i = 0; i < 4; i++)
        #pragma unroll
        for (int j = 0; j < 4; j++) {
            int col = n0 + wn + j * 16 + l15;
            float b = bo[col];
            #pragma unroll
            for (int r = 0; r < 4; r++) {
                int row = m0 + wm + i * 16 + quad * 4 + r;
                out[(size_t)row * DIM + col] = acc[i][j][r] + b;
            }
        }
}

// ---------------- causal flash attention (R4 structure — measured optimum) ----------------
// Block = 4 waves x 16 q-rows; BK=128. Sᵀ = K·Qᵀ (per-lane softmax denom; Q
// pre-scaled by beta*log2e => p = exp2(s)). K AND V tiles staged via
// global_load_lds in fragment-packed layout (linear conflict-free b128 reads).
// LDS 48 KB -> 3 blocks/CU (12 waves). head = id&15 pins 2 heads/XCD (K/V
// L2-resident: FETCH 12 MB proven R4). qt = 63-(id>>4): heavy blocks first,
// light blocks backfill (1024 blocks > 768 slots). DO NOT: pair complementary
// qt at 2 blocks/CU (R5, -26%), drop staging (R6, -131%), hold V in regs
// under a VGPR cap (R7 spill, -154%).
__global__ __launch_bounds__(256, 4) void attention_kernel(
        const bf16* __restrict__ Qh, const bf16* __restrict__ Kh,
        const bf16* __restrict__ Vt, bf16* __restrict__ Oa) {
    __shared__ __align__(16) bf16 Ksh[8192];     // 16 KB: frag t = keygrp*2 + khalf
    __shared__ __align__(16) bf16 Vsh[8192];     // 16 KB: frag t = dgrp*4 + kseg
    __shared__ __align__(16) bf16 Ps[4][2048];   // 4 KB/wave: frag s = key/32
    const int tid = threadIdx.x, wave = tid >> 6, lane = tid & 63;
    const int l15 = lane & 15, quad = lane >> 4;
    const int id = blockIdx.x;
    const int head = id & 15;                    // XCD id&7 serves heads {h, h+8}
    const int qt = 63 - (id >> 4);               // heavy-first
    const int qw = qt * 64 + wave * 16;          // wave's q-row base
    const size_t hoff = (size_t)head * SEQ * DHEAD;
    const bf16* Qb = Qh + hoff;
    const bf16* Kb = Kh + hoff;
    const bf16* Vb = Vt + hoff;                  // [d][seq]

    // Q as B-operand fragments: lane n = l15 -> q-row qw+l15, k along d
    short8 bq[2];
    #pragma unroll
    for (int s = 0; s < 2; s++)
        bq[s] = *reinterpret_cast<const short8*>(
            Qb + (size_t)(qw + l15) * DHEAD + s * 32 + quad * 8);

    floatx4 acc_o[4];                            // Oᵀ: d = c*16+quad*4+r, q = l15
    #pragma unroll
    for (int c = 0; c < 4; c++) acc_o[c] = (floatx4){0.f, 0.f, 0.f, 0.f};
    float l_part = 0.f;                          // per-lane softmax denom partial

    const int ntiles = (qt + 2) >> 1;            // BK=128: keys 0..qt*64+63
    for (int kt = 0; kt < ntiles; kt++) {
        const int kbase = kt * 128;
        __syncthreads();                         // prev-tile readers done
        #pragma unroll
        for (int j = 0; j < 4; j++) {
            int t = wave * 4 + j;                // t = 0..15 across 4 waves
            gll16(Kb + (size_t)(kbase + (t >> 1) * 16 + l15) * DHEAD + (t & 1) * 32 + quad * 8,
                  &Ksh[t * 512]);
            gll16(Vb + (size_t)((t >> 2) * 16 + l15) * SEQ + kbase + (t & 3) * 32 + quad * 8,
                  &Vsh[t * 512]);
        }
        __syncthreads();                         // staged tiles visible

        // Sᵀ = K·Qᵀ: linear conflict-free b128 LDS reads
        floatx4 st[8];
        #pragma unroll
        for (int c = 0; c < 8; c++) st[c] = (floatx4){0.f, 0.f, 0.f, 0.f};
        #pragma unroll
        for (int c = 0; c < 8; c++) {
            short8 ak0 = *reinterpret_cast<const short8*>(&Ksh[(c * 2 + 0) * 512 + lane * 8]);
            short8 ak1 = *reinterpret_cast<const short8*>(&Ksh[(c * 2 + 1) * 512 + lane * 8]);
            st[c] = __builtin_amdgcn_mfma_f32_16x16x32_bf16(ak0, bq[0], st[c], 0, 0, 0);
            st[c] = __builtin_amdgcn_mfma_f32_16x16x32_bf16(ak1, bq[1], st[c], 0, 0, 0);
        }
        // causal mask: key = kbase + c*16 + quad*4 + r, q = qw + l15
        if (kbase + 127 > qw) {                  // wave-uniform
            int base0 = kbase + quad * 4 - qw - l15;
            #pragma unroll
            for (int c = 0; c < 8; c++) {
                int base = base0 + c * 16;
                #pragma unroll
                for (int r = 0; r < 4; r++)
                    if (base + r > 0) st[c][r] = -1e30f;
            }
        }
        // p = exp2(s); per-lane denom; pack into fragment-layout Ps (b64 writes)
        #pragma unroll
        for (int c = 0; c < 8; c++) {
            float p0 = exp2f(st[c][0]);
            float p1 = exp2f(st[c][1]);
            float p2 = exp2f(st[c][2]);
            float p3 = exp2f(st[c][3]);
            l_part += (p0 + p1) + (p2 + p3);
            int elem = (c >> 1) * 512
                     + (l15 + 16 * ((c & 1) * 2 + (quad >> 1))) * 8 + (quad & 1) * 4;
            *reinterpret_cast<uint2*>(&Ps[wave][elem]) = pack4bf(p0, p1, p2, p3);
        }
        // Oᵀ += Vᵀ·Pᵀ: A-frag = Vᵀ d-rows, B-frag = Pᵀ (both linear b128)
        #pragma unroll
        for (int s = 0; s < 4; s++) {
            short8 bp = *reinterpret_cast<const short8*>(&Ps[wave][s * 512 + lane * 8]);
            #pragma unroll
            for (int c = 0; c < 4; c++) {
                short8 av = *reinterpret_cast<const short8*>(&Vsh[(c * 4 + s) * 512 + lane * 8]);
                acc_o[c] = __builtin_amdgcn_mfma_f32_16x16x32_bf16(av, bp, acc_o[c], 0, 0, 0);
            }
        }
    }
    // denom: sum the 4 quad-lanes holding this q-row
    float l = l_part;
    l += __shfl_xor(l, 16, 64);
    l += __shfl_xor(l, 32, 64);
    float rcp = 1.0f / l;
    // write O row-major [SEQ][INNER]: col q = qw+l15, rows d = c*16+quad*4+r
    const int q = qw + l15;
    #pragma unroll
    for (int c = 0; c < 4; c++) {
        uint2 v = pack4bf(acc_o[c][0] * rcp, acc_o[c][1] * rcp,
                          acc_o[c][2] * rcp, acc_o[c][3] * rcp);
        *reinterpret_cast<uint2*>(Oa + (size_t)q * INNER + head * DHEAD + c * 16 + quad * 4) = v;
    }
}

extern "C" void kernel_launch(void* const* d_in, const int* in_sizes, int n_in,
                              void* d_out, int out_size, void* d_ws, size_t ws_size,
                              hipStream_t stream) {
    const float* x  = (const float*)d_in[0];
    const float* Wq = (const float*)d_in[1];
    const float* Wk = (const float*)d_in[2];
    const float* Wv = (const float*)d_in[3];
    const float* Wo = (const float*)d_in[4];
    const float* bo = (const float*)d_in[5];
    float* out = (float*)d_out;

    char* ws = (char*)d_ws;
    size_t off = 0;
    bf16* xb  = (bf16*)(ws + off); off += (size_t)SEQ * DIM * 2;
    bf16* Wqt = (bf16*)(ws + off); off += (size_t)DIM * INNER * 2;
    bf16* Wkt = (bf16*)(ws + off); off += (size_t)DIM * INNER * 2;
    bf16* Wvt = (bf16*)(ws + off); off += (size_t)DIM * INNER * 2;
    bf16* Wot = (bf16*)(ws + off); off += (size_t)INNER * DIM * 2;
    bf16* Qh  = (bf16*)(ws + off); off += (size_t)NHEADS * SEQ * DHEAD * 2;
    bf16* Kh  = (bf16*)(ws + off); off += (size_t)NHEADS * SEQ * DHEAD * 2;
    bf16* Vtr = (bf16*)(ws + off); off += (size_t)NHEADS * DHEAD * SEQ * 2;
    bf16* Oa  = (bf16*)(ws + off); off += (size_t)SEQ * INNER * 2;  // ~48 MB total

    convert_x_kernel<<<(SEQ * DIM) / 1024, 256, 0, stream>>>(x, xb);
    transpose_w_kernel<<<dim3(32, 32, 4), dim3(32, 8), 0, stream>>>(Wq, Wk, Wv, Wo,
                                                                    Wqt, Wkt, Wvt, Wot);
    qkv_gemm_kernel<<<dim3(8, 32, 3), 256, 0, stream>>>(xb, Wqt, Wkt, Wvt, Qh, Kh, Vtr);
    attention_kernel<<<1024, 256, 0, stream>>>(Qh, Kh, Vtr, Oa);
    out_gemm_kernel<<<dim3(8, 32), 256, 0, stream>>>(Oa, Wot, bo, out);
}

// Round 9
// 257.249 us; speedup vs baseline: 1.5222x; 1.0385x over previous
//
#include <hip/hip_runtime.h>
#include <hip/hip_bf16.h>
#include <stdint.h>
#include <math.h>

#define SEQ 4096
#define DIM 1024
#define NHEADS 16
#define DHEAD 64
#define INNER 1024

typedef __hip_bfloat16 bf16;
typedef __attribute__((ext_vector_type(8))) short short8;
typedef __attribute__((ext_vector_type(4))) float floatx4;

// async global->LDS, 16B per lane; lane i's 16B lands at dest + i*16.
__device__ __forceinline__ void gll16(const bf16* g, bf16* l) {
    __builtin_amdgcn_global_load_lds(
        (const __attribute__((address_space(1))) unsigned int*)g,
        (__attribute__((address_space(3))) unsigned int*)l,
        16, 0, 0);
}

__device__ __forceinline__ unsigned short f2bf_bits(float f) {
    bf16 h = __float2bfloat16(f);
    return *reinterpret_cast<unsigned short*>(&h);
}

__device__ __forceinline__ uint2 pack4bf(float a, float b, float c, float d) {
    __hip_bfloat162 lo = __float22bfloat162_rn(float2{a, b});
    __hip_bfloat162 hi = __float22bfloat162_rn(float2{c, d});
    uint2 r;
    r.x = *reinterpret_cast<unsigned*>(&lo);
    r.y = *reinterpret_cast<unsigned*>(&hi);
    return r;
}

// ---------------- prep: z=0..3 weight transpose+convert; z=4 x convert ----------------
__global__ __launch_bounds__(256) void prep_kernel(
        const float* __restrict__ x, const float* __restrict__ W0,
        const float* __restrict__ W1, const float* __restrict__ W2,
        const float* __restrict__ W3, bf16* __restrict__ xb,
        bf16* __restrict__ T0, bf16* __restrict__ T1,
        bf16* __restrict__ T2, bf16* __restrict__ T3) {
    const int tid = threadIdx.x + threadIdx.y * blockDim.x;  // 0..255
    if (blockIdx.z == 4) {
        // convert x: block (bx,by) -> chunk (by*32+bx) of 4096 floats
        int chunk = blockIdx.y * 32 + blockIdx.x;
        int base = chunk * 4096 + tid * 4;
        #pragma unroll
        for (int r = 0; r < 4; r++) {
            int i = base + r * 1024;
            float4 f = *reinterpret_cast<const float4*>(x + i);
            unsigned long long p = (unsigned long long)f2bf_bits(f.x)
                                 | ((unsigned long long)f2bf_bits(f.y) << 16)
                                 | ((unsigned long long)f2bf_bits(f.z) << 32)
                                 | ((unsigned long long)f2bf_bits(f.w) << 48);
            *reinterpret_cast<unsigned long long*>(xb + i) = p;
        }
        return;
    }
    const float* W; bf16* T;
    switch (blockIdx.z) {
        case 0:  W = W0; T = T0; break;
        case 1:  W = W1; T = T1; break;
        case 2:  W = W2; T = T2; break;
        default: W = W3; T = T3; break;
    }
    __shared__ float tile[32][33];
    int k0 = blockIdx.x * 32, n0 = blockIdx.y * 32;
    int tx = threadIdx.x, ty = threadIdx.y;
    #pragma unroll
    for (int i = 0; i < 4; i++)
        tile[ty + 8 * i][tx] = W[(size_t)(k0 + ty + 8 * i) * 1024 + n0 + tx];
    __syncthreads();
    #pragma unroll
    for (int i = 0; i < 4; i++)
        T[(size_t)(n0 + ty + 8 * i) * 1024 + k0 + tx] = __float2bfloat16(tile[tx][ty + 8 * i]);
}

// ---------------- 128x128 bf16 MFMA GEMM tile body (K=1024), m97-style ----------------
__device__ __forceinline__ void gemm128_body(const bf16* __restrict__ A,
                                             const bf16* __restrict__ Bt,
                                             int m0, int n0, floatx4 acc[4][4]) {
    __shared__ __align__(16) bf16 As[8192];
    __shared__ __align__(16) bf16 Bs[8192];
    const int tid = threadIdx.x;
    const int wave = tid >> 6;
    const int lane = tid & 63;
    const int l15 = lane & 15;
    const int quad = lane >> 4;

    #pragma unroll
    for (int i = 0; i < 4; i++)
        #pragma unroll
        for (int j = 0; j < 4; j++)
            acc[i][j] = (floatx4){0.f, 0.f, 0.f, 0.f};

    for (int k0 = 0; k0 < 1024; k0 += 64) {
        __syncthreads();
        #pragma unroll
        for (int j = 0; j < 4; j++) {
            int t = wave * 4 + j;
            int row = (t >> 1) * 16 + l15;
            int kb = (t & 1) * 32 + quad * 8;
            gll16(A + (size_t)(m0 + row) * 1024 + k0 + kb, &As[t * 512]);
            gll16(Bt + (size_t)(n0 + row) * 1024 + k0 + kb, &Bs[t * 512]);
        }
        __syncthreads();
        #pragma unroll
        for (int ks = 0; ks < 2; ks++) {
            short8 af[4], bfr[4];
            #pragma unroll
            for (int i = 0; i < 4; i++)
                af[i] = *reinterpret_cast<const short8*>(
                    &As[((((wave >> 1) * 4 + i) * 2 + ks) * 512) + lane * 8]);
            #pragma unroll
            for (int j = 0; j < 4; j++)
                bfr[j] = *reinterpret_cast<const short8*>(
                    &Bs[((((wave & 1) * 4 + j) * 2 + ks) * 512) + lane * 8]);
            #pragma unroll
            for (int i = 0; i < 4; i++)
                #pragma unroll
                for (int j = 0; j < 4; j++)
                    acc[i][j] = __builtin_amdgcn_mfma_f32_16x16x32_bf16(af[i], bfr[j], acc[i][j], 0, 0, 0);
        }
    }
}

// ---------------- QKV projection ----------------
// z=0: Q (scaled by beta*log2e so attention uses raw v_exp_f32; [h][seq][64])
// z=1: K ([h][seq][64])
// z=2: V written TRANSPOSED directly: Vt[h][d][seq] (b64 packed stores).
__global__ __launch_bounds__(256) void qkv_gemm_kernel(
        const bf16* __restrict__ xb,
        const bf16* __restrict__ Wqt, const bf16* __restrict__ Wkt, const bf16* __restrict__ Wvt,
        bf16* __restrict__ Qh, bf16* __restrict__ Kh, bf16* __restrict__ Vt) {
    const bf16* Bt;
    if (blockIdx.z == 0)      Bt = Wqt;
    else if (blockIdx.z == 1) Bt = Wkt;
    else                      Bt = Wvt;
    int n0 = blockIdx.x * 128, m0 = blockIdx.y * 128;
    floatx4 acc[4][4];
    gemm128_body(xb, Bt, m0, n0, acc);

    const int tid = threadIdx.x, wave = tid >> 6, lane = tid & 63;
    const int l15 = lane & 15, quad = lane >> 4;
    const int wm = (wave >> 1) * 64, wn = (wave & 1) * 64;
    if (blockIdx.z == 2) {
        #pragma unroll
        for (int i = 0; i < 4; i++)
            #pragma unroll
            for (int j = 0; j < 4; j++) {
                int col = n0 + wn + j * 16 + l15;
                int h = col >> 6, d = col & 63;
                int row0 = m0 + wm + i * 16 + quad * 4;
                uint2 v = pack4bf(acc[i][j][0], acc[i][j][1], acc[i][j][2], acc[i][j][3]);
                *reinterpret_cast<uint2*>(Vt + ((size_t)h * DHEAD + d) * SEQ + row0) = v;
            }
    } else {
        bf16* O = (blockIdx.z == 0) ? Qh : Kh;
        float scale = (blockIdx.z == 0) ? 0.125f * 1.4426950408889634f : 1.0f;
        #pragma unroll
        for (int i = 0; i < 4; i++)
            #pragma unroll
            for (int j = 0; j < 4; j++) {
                int col = n0 + wn + j * 16 + l15;
                int h = col >> 6, d = col & 63;
                #pragma unroll
                for (int r = 0; r < 4; r++) {
                    int row = m0 + wm + i * 16 + quad * 4 + r;
                    O[((size_t)h * SEQ + row) * DHEAD + d] = __float2bfloat16(acc[i][j][r] * scale);
                }
            }
    }
}

// ---------------- output projection: out = Oa @ Wo + bo (fp32 out) ----------------
__global__ __launch_bounds__(256) void out_gemm_kernel(
        const bf16* __restrict__ Oa, const bf16* __restrict__ Wot,
        const float* __restrict__ bo, float* __restrict__ out) {
    int n0 = blockIdx.x * 128, m0 = blockIdx.y * 128;
    floatx4 acc[4][4];
    gemm128_body(Oa, Wot, m0, n0, acc);

    const int tid = threadIdx.x, wave = tid >> 6, lane = tid & 63;
    const int l15 = lane & 15, quad = lane >> 4;
    const int wm = (wave >> 1) * 64, wn = (wave & 1) * 64;
    #pragma unroll
    for (int i = 0; i < 4; i++)
        #pragma unroll
        for (int j = 0; j < 4; j++) {
            int col = n0 + wn + j * 16 + l15;
            float b = bo[col];
            #pragma unroll
            for (int r = 0; r < 4; r++) {
                int row = m0 + wm + i * 16 + quad * 4 + r;
                out[(size_t)row * DIM + col] = acc[i][j][r] + b;
            }
        }
}

// ---------------- causal flash attention (R4 structure — measured optimum) ----------------
// Block = 4 waves x 16 q-rows; BK=128. Sᵀ = K·Qᵀ (per-lane softmax denom; Q
// pre-scaled by beta*log2e => p = v_exp_f32(s) via __builtin_amdgcn_exp2f — do
// NOT use exp2f (precise libcall, +15 µs measured R8) or carry a per-score mul).
// K AND V tiles staged via global_load_lds, fragment-packed (linear b128 reads).
// LDS 48 KB -> 3 blocks/CU. head = id&15 pins 2 heads/XCD (FETCH 12 MB, R4).
// qt = 63-(id>>4): heavy blocks first, light backfill. DO NOT: pair
// complementary qt at 2 blocks/CU (R5), drop staging (R6), V in regs (R7 spill).
__global__ __launch_bounds__(256, 4) void attention_kernel(
        const bf16* __restrict__ Qh, const bf16* __restrict__ Kh,
        const bf16* __restrict__ Vt, bf16* __restrict__ Oa) {
    __shared__ __align__(16) bf16 Ksh[8192];     // 16 KB: frag t = keygrp*2 + khalf
    __shared__ __align__(16) bf16 Vsh[8192];     // 16 KB: frag t = dgrp*4 + kseg
    __shared__ __align__(16) bf16 Ps[4][2048];   // 4 KB/wave: frag s = key/32
    const int tid = threadIdx.x, wave = tid >> 6, lane = tid & 63;
    const int l15 = lane & 15, quad = lane >> 4;
    const int id = blockIdx.x;
    const int head = id & 15;                    // XCD id&7 serves heads {h, h+8}
    const int qt = 63 - (id >> 4);               // heavy-first
    const int qw = qt * 64 + wave * 16;          // wave's q-row base
    const size_t hoff = (size_t)head * SEQ * DHEAD;
    const bf16* Qb = Qh + hoff;
    const bf16* Kb = Kh + hoff;
    const bf16* Vb = Vt + hoff;                  // [d][seq]

    // Q as B-operand fragments: lane n = l15 -> q-row qw+l15, k along d
    short8 bq[2];
    #pragma unroll
    for (int s = 0; s < 2; s++)
        bq[s] = *reinterpret_cast<const short8*>(
            Qb + (size_t)(qw + l15) * DHEAD + s * 32 + quad * 8);

    floatx4 acc_o[4];                            // Oᵀ: d = c*16+quad*4+r, q = l15
    #pragma unroll
    for (int c = 0; c < 4; c++) acc_o[c] = (floatx4){0.f, 0.f, 0.f, 0.f};
    float l_part = 0.f;                          // per-lane softmax denom partial

    const int ntiles = (qt + 2) >> 1;            // BK=128: keys 0..qt*64+63
    for (int kt = 0; kt < ntiles; kt++) {
        const int kbase = kt * 128;
        __syncthreads();                         // prev-tile readers done
        #pragma unroll
        for (int j = 0; j < 4; j++) {
            int t = wave * 4 + j;                // t = 0..15 across 4 waves
            gll16(Kb + (size_t)(kbase + (t >> 1) * 16 + l15) * DHEAD + (t & 1) * 32 + quad * 8,
                  &Ksh[t * 512]);
            gll16(Vb + (size_t)((t >> 2) * 16 + l15) * SEQ + kbase + (t & 3) * 32 + quad * 8,
                  &Vsh[t * 512]);
        }
        __syncthreads();                         // staged tiles visible

        // Sᵀ = K·Qᵀ: linear conflict-free b128 LDS reads
        floatx4 st[8];
        #pragma unroll
        for (int c = 0; c < 8; c++) st[c] = (floatx4){0.f, 0.f, 0.f, 0.f};
        #pragma unroll
        for (int c = 0; c < 8; c++) {
            short8 ak0 = *reinterpret_cast<const short8*>(&Ksh[(c * 2 + 0) * 512 + lane * 8]);
            short8 ak1 = *reinterpret_cast<const short8*>(&Ksh[(c * 2 + 1) * 512 + lane * 8]);
            st[c] = __builtin_amdgcn_mfma_f32_16x16x32_bf16(ak0, bq[0], st[c], 0, 0, 0);
            st[c] = __builtin_amdgcn_mfma_f32_16x16x32_bf16(ak1, bq[1], st[c], 0, 0, 0);
        }
        // causal mask: key = kbase + c*16 + quad*4 + r, q = qw + l15
        if (kbase + 127 > qw) {                  // wave-uniform
            int base0 = kbase + quad * 4 - qw - l15;
            #pragma unroll
            for (int c = 0; c < 8; c++) {
                int base = base0 + c * 16;
                #pragma unroll
                for (int r = 0; r < 4; r++)
                    if (base + r > 0) st[c][r] = -1e30f;
            }
        }
        // p = 2^s: raw v_exp_f32 (masked -> 2^-1e30 = 0); per-lane denom; pack Ps
        #pragma unroll
        for (int c = 0; c < 8; c++) {
            float p0 = __builtin_amdgcn_exp2f(st[c][0]);
            float p1 = __builtin_amdgcn_exp2f(st[c][1]);
            float p2 = __builtin_amdgcn_exp2f(st[c][2]);
            float p3 = __builtin_amdgcn_exp2f(st[c][3]);
            l_part += (p0 + p1) + (p2 + p3);
            int elem = (c >> 1) * 512
                     + (l15 + 16 * ((c & 1) * 2 + (quad >> 1))) * 8 + (quad & 1) * 4;
            *reinterpret_cast<uint2*>(&Ps[wave][elem]) = pack4bf(p0, p1, p2, p3);
        }
        // Oᵀ += Vᵀ·Pᵀ: A-frag = Vᵀ d-rows, B-frag = Pᵀ (both linear b128)
        #pragma unroll
        for (int s = 0; s < 4; s++) {
            short8 bp = *reinterpret_cast<const short8*>(&Ps[wave][s * 512 + lane * 8]);
            #pragma unroll
            for (int c = 0; c < 4; c++) {
                short8 av = *reinterpret_cast<const short8*>(&Vsh[(c * 4 + s) * 512 + lane * 8]);
                acc_o[c] = __builtin_amdgcn_mfma_f32_16x16x32_bf16(av, bp, acc_o[c], 0, 0, 0);
            }
        }
    }
    // denom: sum the 4 quad-lanes holding this q-row
    float l = l_part;
    l += __shfl_xor(l, 16, 64);
    l += __shfl_xor(l, 32, 64);
    float rcp = 1.0f / l;
    // write O row-major [SEQ][INNER]: col q = qw+l15, rows d = c*16+quad*4+r
    const int q = qw + l15;
    #pragma unroll
    for (int c = 0; c < 4; c++) {
        uint2 v = pack4bf(acc_o[c][0] * rcp, acc_o[c][1] * rcp,
                          acc_o[c][2] * rcp, acc_o[c][3] * rcp);
        *reinterpret_cast<uint2*>(Oa + (size_t)q * INNER + head * DHEAD + c * 16 + quad * 4) = v;
    }
}

extern "C" void kernel_launch(void* const* d_in, const int* in_sizes, int n_in,
                              void* d_out, int out_size, void* d_ws, size_t ws_size,
                              hipStream_t stream) {
    const float* x  = (const float*)d_in[0];
    const float* Wq = (const float*)d_in[1];
    const float* Wk = (const float*)d_in[2];
    const float* Wv = (const float*)d_in[3];
    const float* Wo = (const float*)d_in[4];
    const float* bo = (const float*)d_in[5];
    float* out = (float*)d_out;

    char* ws = (char*)d_ws;
    size_t off = 0;
    bf16* xb  = (bf16*)(ws + off); off += (size_t)SEQ * DIM * 2;
    bf16* Wqt = (bf16*)(ws + off); off += (size_t)DIM * INNER * 2;
    bf16* Wkt = (bf16*)(ws + off); off += (size_t)DIM * INNER * 2;
    bf16* Wvt = (bf16*)(ws + off); off += (size_t)DIM * INNER * 2;
    bf16* Wot = (bf16*)(ws + off); off += (size_t)INNER * DIM * 2;
    bf16* Qh  = (bf16*)(ws + off); off += (size_t)NHEADS * SEQ * DHEAD * 2;
    bf16* Kh  = (bf16*)(ws + off); off += (size_t)NHEADS * SEQ * DHEAD * 2;
    bf16* Vtr = (bf16*)(ws + off); off += (size_t)NHEADS * DHEAD * SEQ * 2;
    bf16* Oa  = (bf16*)(ws + off); off += (size_t)SEQ * INNER * 2;  // ~48 MB total

    prep_kernel<<<dim3(32, 32, 5), dim3(32, 8), 0, stream>>>(x, Wq, Wk, Wv, Wo,
                                                             xb, Wqt, Wkt, Wvt, Wot);
    qkv_gemm_kernel<<<dim3(8, 32, 3), 256, 0, stream>>>(xb, Wqt, Wkt, Wvt, Qh, Kh, Vtr);
    attention_kernel<<<1024, 256, 0, stream>>>(Qh, Kh, Vtr, Oa);
    out_gemm_kernel<<<dim3(8, 32), 256, 0, stream>>>(Oa, Wot, bo, out);
}